// Round 12
// baseline (4601.088 us; speedup 1.0000x reference)
//
#include <hip/hip_runtime.h>
#include <hip/hip_bf16.h>

// GRU: SEQ=512, B=64, I=512, H=1024, O=512
#define SEQL 512
#define BATCH 64
#define INF 512
#define HID 1024
#define OUTF 512
#define SB (SEQL*BATCH)
#define BH (BATCH*HID)

typedef __attribute__((ext_vector_type(8))) __bf16 bf16x8;
typedef __attribute__((ext_vector_type(4))) float f32x4;

__device__ inline bf16x8 ld_bf8(const void* p) { return *reinterpret_cast<const bf16x8*>(p); }
__device__ inline unsigned short f2bf(float f) { __bf16 b = (__bf16)f; return __builtin_bit_cast(unsigned short, b); }

// Coherent 8B store: relaxed agent-scope atomic -> write-through to IF, no cache maintenance.
__device__ inline void st_u64c(void* p, unsigned long long v) {
    __hip_atomic_store((unsigned long long*)p, v, __ATOMIC_RELAXED, __HIP_MEMORY_SCOPE_AGENT);
}

// ---------------- prep kernels ----------------
__global__ void cvt_f32_bf16(const float* __restrict__ src, unsigned short* __restrict__ dst, int n) {
    int i = (blockIdx.x * blockDim.x + threadIdx.x) * 4;
    if (i < n) {
        float4 v = *reinterpret_cast<const float4*>(src + i);
        ushort4 o = make_ushort4(f2bf(v.x), f2bf(v.y), f2bf(v.z), f2bf(v.w));
        *reinterpret_cast<ushort4*>(dst + i) = o;
    }
}

__global__ void make_bias2(const float* bxz, const float* bhz, const float* bxr,
                           const float* bhr, float* bias2) {
    int i = blockIdx.x * blockDim.x + threadIdx.x;
    if (i < HID) bias2[i] = bxz[i] + bhz[i];
    else if (i < 2*HID) bias2[i] = bxr[i-HID] + bhr[i-HID];
}

__global__ void fail_sentinel(float* o) { o[0] = 1e9f; }

// ---------------- tiled NT GEMM (unchanged, validated) ----------------
__global__ __launch_bounds__(256, 2) void gemm_nt_f32(
        const unsigned short* __restrict__ A, int lda,
        const unsigned short* __restrict__ Bw, int ldb,
        const float* __restrict__ bias,
        float* __restrict__ Cf, int N, int K) {
    __shared__ __align__(16) char lds[32768];
    const int tid = threadIdx.x;
    const int ntn = N >> 7;
    const int bm = blockIdx.x / ntn, bn = blockIdx.x % ntn;
    const int rowbase = bm << 7, colbase = bn << 7;
    const int wave = tid >> 6, lane = tid & 63, lo = lane & 15, hi = lane >> 4;
    const int vm = wave >> 1, vn = wave & 1;

    auto stage = [&](int abase, int k0) {
        #pragma unroll
        for (int i = 0; i < 2; i++) {
            int linear = i * 256 + tid;
            int r = linear >> 2, s = linear & 3;
            int c = (s - (r >> 1)) & 3;
            const unsigned short* ga = A + (size_t)(rowbase + r) * lda + k0 + c * 8;
            const unsigned short* gb = Bw + (size_t)(colbase + r) * ldb + k0 + c * 8;
            __builtin_amdgcn_global_load_lds(
                (const __attribute__((address_space(1))) unsigned int*)ga,
                (__attribute__((address_space(3))) unsigned int*)(lds + abase + linear * 16), 16, 0, 0);
            __builtin_amdgcn_global_load_lds(
                (const __attribute__((address_space(1))) unsigned int*)gb,
                (__attribute__((address_space(3))) unsigned int*)(lds + 16384 + abase + linear * 16), 16, 0, 0);
        }
    };

    f32x4 acc[4][4] = {};
    const int nk = K >> 5;
    stage(0, 0);
    for (int kt = 0; kt < nk; kt++) {
        __syncthreads();
        if (kt + 1 < nk) stage(((kt + 1) & 1) * 8192, (kt + 1) << 5);
        const char* cA = lds + (kt & 1) * 8192;
        const char* cB = lds + 16384 + (kt & 1) * 8192;
        bf16x8 af[4], bfr[4];
        #pragma unroll
        for (int m = 0; m < 4; m++) {
            int r = vm * 64 + m * 16 + lo;
            af[m] = ld_bf8(cA + r * 64 + 16 * ((hi + (r >> 1)) & 3));
        }
        #pragma unroll
        for (int n = 0; n < 4; n++) {
            int r = vn * 64 + n * 16 + lo;
            bfr[n] = ld_bf8(cB + r * 64 + 16 * ((hi + (r >> 1)) & 3));
        }
        #pragma unroll
        for (int m = 0; m < 4; m++)
            #pragma unroll
            for (int n = 0; n < 4; n++)
                acc[m][n] = __builtin_amdgcn_mfma_f32_16x16x32_bf16(af[m], bfr[n], acc[m][n], 0, 0, 0);
        __syncthreads();
    }

    #pragma unroll
    for (int n = 0; n < 4; n++) {
        int col = colbase + vn * 64 + n * 16 + lo;
        float bv = bias[col];
        #pragma unroll
        for (int m = 0; m < 4; m++)
            #pragma unroll
            for (int r = 0; r < 4; r++) {
                int row = rowbase + vm * 64 + m * 16 + hi * 4 + r;
                Cf[(size_t)row * N + col] = acc[m][n][r] + bv;
            }
    }
}

// ---------------- persistent GRU scan v8: coalesced reg-staged h tile ----------------
// 256 WGs x 192 threads; rb = wid>>6 in 0..3 (16 batch rows, 4 independent scan groups),
// cb = wid&63 (16 h-cols); wave g = gate {z,r,hcand}.
// LDS: [0,96K) wh; [96K,128K) h tile; [128K,131K) Px; [131K,131.5K) T repack.
// ROUND-11 POST-MORTEM: global_load_lds + fragment-major forces 16B loads at 2048B lane
// stride -> ~524K uncoalesced L2 transactions/step, the dominant hidden cost. PROVEN bank
// rule (r7/r9, 2x measured): per quarter-wave the 16 LDS addresses must cover one
// contiguous 256B block. v8 decouples global and LDS orders via REG staging:
//   load:  u=(it*192+tid), row=u>>6, slot=u&63(+64 for half B); 64 consecutive lanes read
//          1024B contiguous global (full 128B-line coalescing, 8x fewer transactions).
//   write: ds_write_b128 to slot*256 + ((row+slot)&15)*16 -> banks 4*((row+slot)&7),
//          consecutive slots -> 8 banks x2 = 2-way (free, m136).
//   read:  frag kb: kb*1024 + hi*256 + (((lo+kb*4+hi)&15)<<4) -- within-256B permutation
//          of the proven-free linear pattern; each lane gets its (row=lo, slot=kb*4+hi).
// Sync (validated r8/r10/r11): split-half flags (A=producers 0..31); loads-A issue ->
// poll-B (A lands under RTT) -> loads-B -> writes -> barrier. Producer: T-repack -> one
// 8B coherent store/lane -> vmcnt(0) -> flag store. Cached h loads + startup buffer_inv.
__global__ __launch_bounds__(192, 1) void gru_scan(
        const unsigned short* __restrict__ Whc,   // [3][H][H]
        const unsigned short* __restrict__ Wxc,   // [3][H][I]
        const unsigned short* __restrict__ xbf,   // [S*B][I]
        unsigned short* __restrict__ hs,          // [S+1][B][H]
        const float* __restrict__ bias2,          // [2H]
        const float* __restrict__ bxh,
        const float* __restrict__ bhh,
        unsigned int* flags) {                    // [4][64] per-WG step flags
    __shared__ __align__(16) char lds[134656];
    const int tid = threadIdx.x;
    const int wid = blockIdx.x;
    const int rb = wid >> 6;          // 0..3
    const int cb = wid & 63;
    const int g = tid / 64;
    const int lane = tid & 63, lo = lane & 15, hi = lane >> 4;
    const int col = cb * 16 + lo;
    char* whl = lds + g * 32768;                       // this wave's 32 wh frags
    char* hstage = lds + 98304;                        // 32 KB h tile (swizzled units)
    f32x4* Px = (f32x4*)(lds + 131072);                // 3 KB exchange
    unsigned short* T = (unsigned short*)(lds + 134144); // 512 B store-repack

    // ---- stage wh slices into LDS (once) ----
    {
        const unsigned short* ph = Whc + ((size_t)g * HID + col) * HID + hi * 8;
        #pragma unroll
        for (int kb = 0; kb < 32; kb++)
            __builtin_amdgcn_global_load_lds(
                (const __attribute__((address_space(1))) unsigned int*)(ph + kb * 32),
                (__attribute__((address_space(3))) unsigned int*)(whl + kb * 1024 + lane * 16), 16, 0, 0);
    }
    __syncthreads();
    // Kill pre-launch (previous graph replay) L2 lines of hsbuf before the first h read.
    asm volatile("buffer_inv sc0 sc1" ::: "memory");

    const float bzv  = bias2[col];
    const float brv  = bias2[HID + col];
    const float bxhv = bxh[col];
    const float bhhv = bhh[col];
    float hst[4] = {0.f, 0.f, 0.f, 0.f};   // fp32 state: row = rb*16 + hi*4 + r, col
    const unsigned short* wxp = Wxc + ((size_t)g * HID + col) * INF + hi * 8;
    const unsigned int* flA = flags + rb * 64 + (lane & 31);        // half-A producers
    const unsigned int* flB = flags + rb * 64 + 32 + (lane & 31);   // half-B producers

    // x-side preacts for t=0
    f32x4 ax = {0,0,0,0};
    {
        const unsigned short* xp = xbf + ((size_t)(rb * 16 + lo)) * INF + hi * 8;
        #pragma unroll
        for (int kb = 0; kb < 16; kb++)
            ax = __builtin_amdgcn_mfma_f32_16x16x32_bf16(ld_bf8(xp + kb * 32), ld_bf8(wxp + kb * 32), ax, 0, 0, 0);
    }

    for (int t = 0; t < SEQL; t++) {
        // --- stage h[t]: coalesced reg loads (A half; poll-A was at end of prev iter) ---
        uint4 hvA[6], hvB[6];
        if (t > 0) {
            const unsigned short* hsrc = hs + (size_t)t * BH + (size_t)(rb * 16) * HID;
            #pragma unroll
            for (int it = 0; it < 6; it++) {            // half A: slots 0..63 (k 0..511)
                int u = it * 192 + tid;
                if (u < 1024) {
                    int row = u >> 6, slot = u & 63;
                    hvA[it] = *reinterpret_cast<const uint4*>(hsrc + (size_t)row * HID + slot * 8);
                }
            }
            // --- poll half-B producers; A loads land under this RTT ---
            {
                unsigned int tgt = (unsigned int)t;
                while (!__all(__hip_atomic_load(flB, __ATOMIC_RELAXED, __HIP_MEMORY_SCOPE_AGENT) >= tgt))
                    __builtin_amdgcn_s_sleep(1);
            }
            #pragma unroll
            for (int it = 0; it < 6; it++) {            // half B: slots 64..127
                int u = it * 192 + tid;
                if (u < 1024) {
                    int row = u >> 6, slot = 64 + (u & 63);
                    hvB[it] = *reinterpret_cast<const uint4*>(hsrc + (size_t)row * HID + slot * 8);
                }
            }
            // --- ds_writes: 2-way-free swizzled pattern ---
            #pragma unroll
            for (int it = 0; it < 6; it++) {
                int u = it * 192 + tid;
                if (u < 1024) {
                    int row = u >> 6, slot = u & 63;
                    *reinterpret_cast<uint4*>(hstage + slot * 256 + ((row + slot) & 15) * 16) = hvA[it];
                }
            }
            #pragma unroll
            for (int it = 0; it < 6; it++) {
                int u = it * 192 + tid;
                if (u < 1024) {
                    int row = u >> 6, slot = 64 + (u & 63);
                    *reinterpret_cast<uint4*>(hstage + slot * 256 + ((row + slot) & 15) * 16) = hvB[it];
                }
            }
        }
        __syncthreads();   // all writes visible

        // --- h-side preacts: within-256B permuted reads (conflict-free class) ---
        f32x4 ah = {0,0,0,0};
        if (t > 0) {
            #pragma unroll
            for (int kb = 0; kb < 32; kb++) {
                bf16x8 w = ld_bf8(whl + kb * 1024 + lane * 16);
                bf16x8 a = ld_bf8(hstage + kb * 1024 + hi * 256 + (((lo + kb * 4 + hi) & 15) << 4));
                ah = __builtin_amdgcn_mfma_f32_16x16x32_bf16(a, w, ah, 0, 0, 0);
            }
        }

        // --- exchange r-pre and both hcand parts via LDS ---
        if (g == 1) {
            f32x4 v;
            #pragma unroll
            for (int r = 0; r < 4; r++) v[r] = ah[r] + ax[r] + brv;
            Px[0 * 64 + lane] = v;
        } else if (g == 2) {
            f32x4 v, w;
            #pragma unroll
            for (int r = 0; r < 4; r++) { v[r] = ah[r] + bhhv; w[r] = ax[r] + bxhv; }
            Px[1 * 64 + lane] = v;
            Px[2 * 64 + lane] = w;
        }
        __syncthreads();

        // --- finalize by wave 0: gates -> new h -> T-repack -> ONE 8B coherent store/lane ---
        if (g == 0) {
            unsigned short* hdst = hs + (size_t)(t + 1) * BH;
            f32x4 pr = Px[0 * 64 + lane];
            f32x4 ph_ = Px[1 * 64 + lane];
            f32x4 px_ = Px[2 * 64 + lane];
            #pragma unroll
            for (int r = 0; r < 4; r++) {
                float z  = 1.f / (1.f + __expf(-(ah[r] + ax[r] + bzv)));
                float rr = 1.f / (1.f + __expf(-pr[r]));
                float hc = tanhf(px_[r] + rr * ph_[r]);
                hst[r] = (1.f - z) * hst[r] + z * hc;
                T[(hi * 4 + r) * 16 + lo] = f2bf(hst[r]);   // T[row16][col16]
            }
            asm volatile("s_waitcnt lgkmcnt(0)" ::: "memory");  // cross-lane T writes complete
            int row = lane >> 2, q = lane & 3;
            unsigned long long val = *(const unsigned long long*)(T + row * 16 + q * 4);
            st_u64c(hdst + (size_t)(rb * 16 + row) * HID + cb * 16 + q * 4, val);
            asm volatile("s_waitcnt vmcnt(0)" ::: "memory");    // h-store at the IF
        }
        if (tid == 0)
            __hip_atomic_store(flags + rb * 64 + cb, (unsigned int)(t + 1),
                               __ATOMIC_RELAXED, __HIP_MEMORY_SCOPE_AGENT);

        // --- x-prefetch for t+1 (L2-warm) overlaps flag propagation; then poll half A ---
        f32x4 nax = {0,0,0,0};
        if (t + 1 < SEQL) {
            const unsigned short* xp = xbf + ((size_t)(t + 1) * BATCH + rb * 16 + lo) * INF + hi * 8;
            #pragma unroll
            for (int kb = 0; kb < 16; kb++)
                nax = __builtin_amdgcn_mfma_f32_16x16x32_bf16(ld_bf8(xp + kb * 32), ld_bf8(wxp + kb * 32), nax, 0, 0, 0);
            unsigned int tgt = (unsigned int)(t + 1);
            while (!__all(__hip_atomic_load(flA, __ATOMIC_RELAXED, __HIP_MEMORY_SCOPE_AGENT) >= tgt))
                __builtin_amdgcn_s_sleep(1);
        }
        ax = nax;
    }
}

// ---------------- host ----------------
extern "C" void kernel_launch(void* const* d_in, const int* in_sizes, int n_in,
                              void* d_out, int out_size, void* d_ws, size_t ws_size,
                              hipStream_t stream) {
    const float* x   = (const float*)d_in[0];
    const float* Wxz = (const float*)d_in[1];
    const float* bxz = (const float*)d_in[2];
    const float* Whz = (const float*)d_in[3];
    const float* bhz = (const float*)d_in[4];
    const float* Wxr = (const float*)d_in[5];
    const float* bxr = (const float*)d_in[6];
    const float* Whr = (const float*)d_in[7];
    const float* bhr = (const float*)d_in[8];
    const float* Wxh = (const float*)d_in[9];
    const float* bxh = (const float*)d_in[10];
    const float* Whh = (const float*)d_in[11];
    const float* bhh = (const float*)d_in[12];
    const float* Why = (const float*)d_in[13];
    const float* bhy = (const float*)d_in[14];

    char* ws = (char*)d_ws;
    size_t off = 0;
    auto alloc = [&](size_t bytes) { char* p = ws + off; off += (bytes + 255) & ~(size_t)255; return p; };
    unsigned short* Whc   = (unsigned short*)alloc((size_t)3 * HID * HID * 2);
    unsigned short* Wxc   = (unsigned short*)alloc((size_t)3 * HID * INF * 2);
    unsigned short* Whyb  = (unsigned short*)alloc((size_t)OUTF * HID * 2);
    float*          bias2 = (float*)alloc((size_t)2 * HID * 4);
    unsigned short* hsbuf = (unsigned short*)alloc((size_t)(SEQL + 1) * BATCH * HID * 2);
    unsigned int*   flags = (unsigned int*)alloc(1024);
    unsigned short* x_bf  = (unsigned short*)d_out;  // dead until the final GEMM

    if (off > ws_size) {
        fail_sentinel<<<dim3(1), dim3(1), 0, stream>>>((float*)d_out);
        return;
    }

    auto cvt = [&](const float* s, unsigned short* d, size_t n) {
        cvt_f32_bf16<<<dim3((unsigned)((n / 4 + 255) / 256)), dim3(256), 0, stream>>>(s, d, (int)n);
    };
    cvt(x, x_bf, (size_t)SB * INF);
    cvt(Whz, Whc, (size_t)HID * HID);
    cvt(Whr, Whc + (size_t)HID * HID, (size_t)HID * HID);
    cvt(Whh, Whc + (size_t)2 * HID * HID, (size_t)HID * HID);
    cvt(Wxz, Wxc, (size_t)HID * INF);
    cvt(Wxr, Wxc + (size_t)HID * INF, (size_t)HID * INF);
    cvt(Wxh, Wxc + (size_t)2 * HID * INF, (size_t)HID * INF);
    cvt(Why, Whyb, (size_t)OUTF * HID);
    make_bias2<<<dim3(8), dim3(256), 0, stream>>>(bxz, bhz, bxr, bhr, bias2);
    (void)hipMemsetAsync(flags, 0, 1024, stream);   // reset per launch (graph-replay safe)

    gru_scan<<<dim3(256), dim3(192), 0, stream>>>(Whc, Wxc, x_bf, hsbuf, bias2, bxh, bhh, flags);

    gemm_nt_f32<<<dim3((SB / 128) * (OUTF / 128)), dim3(256), 0, stream>>>(
        hsbuf + (size_t)BATCH * HID, HID, Whyb, HID, bhy, (float*)d_out, OUTF, HID);
}

// Round 13
// 3565.716 us; speedup vs baseline: 1.2904x; 1.2904x over previous
//
#include <hip/hip_runtime.h>
#include <hip/hip_bf16.h>

// GRU: SEQ=512, B=64, I=512, H=1024, O=512
#define SEQL 512
#define BATCH 64
#define INF 512
#define HID 1024
#define OUTF 512
#define SB (SEQL*BATCH)
#define BH (BATCH*HID)

typedef __attribute__((ext_vector_type(8))) __bf16 bf16x8;
typedef __attribute__((ext_vector_type(4))) float f32x4;

__device__ inline bf16x8 ld_bf8(const void* p) { return *reinterpret_cast<const bf16x8*>(p); }
__device__ inline unsigned short f2bf(float f) { __bf16 b = (__bf16)f; return __builtin_bit_cast(unsigned short, b); }

// Coherent 8B store: relaxed agent-scope atomic -> write-through to IF, no cache maintenance.
__device__ inline void st_u64c(void* p, unsigned long long v) {
    __hip_atomic_store((unsigned long long*)p, v, __ATOMIC_RELAXED, __HIP_MEMORY_SCOPE_AGENT);
}

// ---------------- prep kernels ----------------
__global__ void cvt_f32_bf16(const float* __restrict__ src, unsigned short* __restrict__ dst, int n) {
    int i = (blockIdx.x * blockDim.x + threadIdx.x) * 4;
    if (i < n) {
        float4 v = *reinterpret_cast<const float4*>(src + i);
        ushort4 o = make_ushort4(f2bf(v.x), f2bf(v.y), f2bf(v.z), f2bf(v.w));
        *reinterpret_cast<ushort4*>(dst + i) = o;
    }
}

__global__ void make_bias2(const float* bxz, const float* bhz, const float* bxr,
                           const float* bhr, float* bias2) {
    int i = blockIdx.x * blockDim.x + threadIdx.x;
    if (i < HID) bias2[i] = bxz[i] + bhz[i];
    else if (i < 2*HID) bias2[i] = bxr[i-HID] + bhr[i-HID];
}

__global__ void fail_sentinel(float* o) { o[0] = 1e9f; }

// ---------------- tiled NT GEMM (unchanged, validated) ----------------
__global__ __launch_bounds__(256, 2) void gemm_nt_f32(
        const unsigned short* __restrict__ A, int lda,
        const unsigned short* __restrict__ Bw, int ldb,
        const float* __restrict__ bias,
        float* __restrict__ Cf, int N, int K) {
    __shared__ __align__(16) char lds[32768];
    const int tid = threadIdx.x;
    const int ntn = N >> 7;
    const int bm = blockIdx.x / ntn, bn = blockIdx.x % ntn;
    const int rowbase = bm << 7, colbase = bn << 7;
    const int wave = tid >> 6, lane = tid & 63, lo = lane & 15, hi = lane >> 4;
    const int vm = wave >> 1, vn = wave & 1;

    auto stage = [&](int abase, int k0) {
        #pragma unroll
        for (int i = 0; i < 2; i++) {
            int linear = i * 256 + tid;
            int r = linear >> 2, s = linear & 3;
            int c = (s - (r >> 1)) & 3;
            const unsigned short* ga = A + (size_t)(rowbase + r) * lda + k0 + c * 8;
            const unsigned short* gb = Bw + (size_t)(colbase + r) * ldb + k0 + c * 8;
            __builtin_amdgcn_global_load_lds(
                (const __attribute__((address_space(1))) unsigned int*)ga,
                (__attribute__((address_space(3))) unsigned int*)(lds + abase + linear * 16), 16, 0, 0);
            __builtin_amdgcn_global_load_lds(
                (const __attribute__((address_space(1))) unsigned int*)gb,
                (__attribute__((address_space(3))) unsigned int*)(lds + 16384 + abase + linear * 16), 16, 0, 0);
        }
    };

    f32x4 acc[4][4] = {};
    const int nk = K >> 5;
    stage(0, 0);
    for (int kt = 0; kt < nk; kt++) {
        __syncthreads();
        if (kt + 1 < nk) stage(((kt + 1) & 1) * 8192, (kt + 1) << 5);
        const char* cA = lds + (kt & 1) * 8192;
        const char* cB = lds + 16384 + (kt & 1) * 8192;
        bf16x8 af[4], bfr[4];
        #pragma unroll
        for (int m = 0; m < 4; m++) {
            int r = vm * 64 + m * 16 + lo;
            af[m] = ld_bf8(cA + r * 64 + 16 * ((hi + (r >> 1)) & 3));
        }
        #pragma unroll
        for (int n = 0; n < 4; n++) {
            int r = vn * 64 + n * 16 + lo;
            bfr[n] = ld_bf8(cB + r * 64 + 16 * ((hi + (r >> 1)) & 3));
        }
        #pragma unroll
        for (int m = 0; m < 4; m++)
            #pragma unroll
            for (int n = 0; n < 4; n++)
                acc[m][n] = __builtin_amdgcn_mfma_f32_16x16x32_bf16(af[m], bfr[n], acc[m][n], 0, 0, 0);
        __syncthreads();
    }

    #pragma unroll
    for (int n = 0; n < 4; n++) {
        int col = colbase + vn * 64 + n * 16 + lo;
        float bv = bias[col];
        #pragma unroll
        for (int m = 0; m < 4; m++)
            #pragma unroll
            for (int r = 0; r < 4; r++) {
                int row = rowbase + vm * 64 + m * 16 + hi * 4 + r;
                Cf[(size_t)row * N + col] = acc[m][n][r] + bv;
            }
    }
}

// ---------------- persistent GRU scan v9: direct register h loads, no h staging ----------------
// 256 WGs x 192 threads; rb = wid>>6 in 0..3 (16 batch rows, 4 independent scan groups),
// cb = wid&63 (16 h-cols); wave g = gate {z,r,hcand}.
// LDS: [0,96K) wh only + [96K..) Px/T. NO h tile (round-12 post-mortem: every LDS
// permutation either breaks coalescing (r8: 2048B-stride 16B transactions), banks (r9/r12:
// 7.6e7 conflicts -- rule: per quarter-wave, b128 addrs must tile ONE contiguous 256B
// block), or needs an extra barrier. v9 deletes the phase: each wave loads its h fragments
// DIRECTLY to registers with plain cached loads (L2-shared across the 3 waves / 8 WGs per
// XCD; first touch misses to IF which is fresh by flag ordering -- r11-validated pattern).
// Plain loads (unlike r3/r4's bypass atomics) are freely hoisted/pipelined by the compiler
// -> ~16 outstanding, latency/MLP instead of latency*N. One __syncthreads per step.
// Ordering: asm "memory" after each poll pins h-load issue behind flag confirm. Px(t+1)
// write-after-read safety: own-WG flag is set by wave0 lane0 AFTER the whole wave passed
// its Px reads (lockstep) -> pollers of t+1 can't race finalize(t).
__global__ __launch_bounds__(192, 1) void gru_scan(
        const unsigned short* __restrict__ Whc,   // [3][H][H]
        const unsigned short* __restrict__ Wxc,   // [3][H][I]
        const unsigned short* __restrict__ xbf,   // [S*B][I]
        unsigned short* __restrict__ hs,          // [S+1][B][H]
        const float* __restrict__ bias2,          // [2H]
        const float* __restrict__ bxh,
        const float* __restrict__ bhh,
        unsigned int* flags) {                    // [4][64] per-WG step flags
    __shared__ __align__(16) char lds[101888];
    const int tid = threadIdx.x;
    const int wid = blockIdx.x;
    const int rb = wid >> 6;          // 0..3
    const int cb = wid & 63;
    const int g = tid / 64;
    const int lane = tid & 63, lo = lane & 15, hi = lane >> 4;
    const int col = cb * 16 + lo;
    char* whl = lds + g * 32768;                         // this wave's 32 wh frags
    f32x4* Px = (f32x4*)(lds + 98304);                   // 3 KB exchange
    unsigned short* T = (unsigned short*)(lds + 101376); // 512 B store-repack

    // ---- stage wh slices into LDS (once) ----
    {
        const unsigned short* ph = Whc + ((size_t)g * HID + col) * HID + hi * 8;
        #pragma unroll
        for (int kb = 0; kb < 32; kb++)
            __builtin_amdgcn_global_load_lds(
                (const __attribute__((address_space(1))) unsigned int*)(ph + kb * 32),
                (__attribute__((address_space(3))) unsigned int*)(whl + kb * 1024 + lane * 16), 16, 0, 0);
    }
    __syncthreads();
    // Kill pre-launch (previous graph replay) L2 lines of hsbuf before the first h read.
    asm volatile("buffer_inv sc0 sc1" ::: "memory");

    const float bzv  = bias2[col];
    const float brv  = bias2[HID + col];
    const float bxhv = bxh[col];
    const float bhhv = bhh[col];
    float hst[4] = {0.f, 0.f, 0.f, 0.f};   // fp32 state: row = rb*16 + hi*4 + r, col
    const unsigned short* wxp = Wxc + ((size_t)g * HID + col) * INF + hi * 8;
    const unsigned int* flA = flags + rb * 64 + (lane & 31);        // half-A producers
    const unsigned int* flB = flags + rb * 64 + 32 + (lane & 31);   // half-B producers

    // x-side preacts for t=0
    f32x4 ax = {0,0,0,0};
    {
        const unsigned short* xp = xbf + ((size_t)(rb * 16 + lo)) * INF + hi * 8;
        #pragma unroll
        for (int kb = 0; kb < 16; kb++)
            ax = __builtin_amdgcn_mfma_f32_16x16x32_bf16(ld_bf8(xp + kb * 32), ld_bf8(wxp + kb * 32), ax, 0, 0, 0);
    }

    for (int t = 0; t < SEQL; t++) {
        // --- h-side preacts: direct cached reg loads, half A (k<512; poll-A at prev iter end) ---
        f32x4 ah = {0,0,0,0};
        if (t > 0) {
            const unsigned short* ap = hs + (size_t)t * BH + (size_t)(rb * 16 + lo) * HID + hi * 8;
            #pragma unroll
            for (int kb = 0; kb < 16; kb++) {
                bf16x8 a = ld_bf8(ap + kb * 32);
                bf16x8 w = ld_bf8(whl + kb * 1024 + lane * 16);
                ah = __builtin_amdgcn_mfma_f32_16x16x32_bf16(a, w, ah, 0, 0, 0);
            }
            // --- poll half-B producers (A loads/MFMAs proceed above this in flight) ---
            {
                unsigned int tgt = (unsigned int)t;
                while (!__all(__hip_atomic_load(flB, __ATOMIC_RELAXED, __HIP_MEMORY_SCOPE_AGENT) >= tgt))
                    __builtin_amdgcn_s_sleep(1);
                asm volatile("" ::: "memory");   // pin half-B loads behind the poll
            }
            #pragma unroll
            for (int kb = 16; kb < 32; kb++) {
                bf16x8 a = ld_bf8(ap + kb * 32);
                bf16x8 w = ld_bf8(whl + kb * 1024 + lane * 16);
                ah = __builtin_amdgcn_mfma_f32_16x16x32_bf16(a, w, ah, 0, 0, 0);
            }
        }

        // --- exchange r-pre and both hcand parts via LDS ---
        if (g == 1) {
            f32x4 v;
            #pragma unroll
            for (int r = 0; r < 4; r++) v[r] = ah[r] + ax[r] + brv;
            Px[0 * 64 + lane] = v;
        } else if (g == 2) {
            f32x4 v, w;
            #pragma unroll
            for (int r = 0; r < 4; r++) { v[r] = ah[r] + bhhv; w[r] = ax[r] + bxhv; }
            Px[1 * 64 + lane] = v;
            Px[2 * 64 + lane] = w;
        }
        __syncthreads();   // the ONLY barrier per step

        // --- finalize by wave 0: gates -> new h -> T-repack -> ONE 8B coherent store/lane ---
        if (g == 0) {
            unsigned short* hdst = hs + (size_t)(t + 1) * BH;
            f32x4 pr = Px[0 * 64 + lane];
            f32x4 ph_ = Px[1 * 64 + lane];
            f32x4 px_ = Px[2 * 64 + lane];
            #pragma unroll
            for (int r = 0; r < 4; r++) {
                float z  = 1.f / (1.f + __expf(-(ah[r] + ax[r] + bzv)));
                float rr = 1.f / (1.f + __expf(-pr[r]));
                float hc = tanhf(px_[r] + rr * ph_[r]);
                hst[r] = (1.f - z) * hst[r] + z * hc;
                T[(hi * 4 + r) * 16 + lo] = f2bf(hst[r]);   // T[row16][col16]
            }
            asm volatile("s_waitcnt lgkmcnt(0)" ::: "memory");  // cross-lane T writes complete
            int row = lane >> 2, q = lane & 3;
            unsigned long long val = *(const unsigned long long*)(T + row * 16 + q * 4);
            st_u64c(hdst + (size_t)(rb * 16 + row) * HID + cb * 16 + q * 4, val);
            asm volatile("s_waitcnt vmcnt(0)" ::: "memory");    // h-store at the IF
        }
        if (tid == 0)
            __hip_atomic_store(flags + rb * 64 + cb, (unsigned int)(t + 1),
                               __ATOMIC_RELAXED, __HIP_MEMORY_SCOPE_AGENT);

        // --- x-prefetch for t+1 (L2-warm) overlaps flag propagation; then poll half A ---
        f32x4 nax = {0,0,0,0};
        if (t + 1 < SEQL) {
            const unsigned short* xp = xbf + ((size_t)(t + 1) * BATCH + rb * 16 + lo) * INF + hi * 8;
            #pragma unroll
            for (int kb = 0; kb < 16; kb++)
                nax = __builtin_amdgcn_mfma_f32_16x16x32_bf16(ld_bf8(xp + kb * 32), ld_bf8(wxp + kb * 32), nax, 0, 0, 0);
            unsigned int tgt = (unsigned int)(t + 1);
            while (!__all(__hip_atomic_load(flA, __ATOMIC_RELAXED, __HIP_MEMORY_SCOPE_AGENT) >= tgt))
                __builtin_amdgcn_s_sleep(1);
            asm volatile("" ::: "memory");   // pin next iter's half-A loads behind the poll
        }
        ax = nax;
    }
}

// ---------------- host ----------------
extern "C" void kernel_launch(void* const* d_in, const int* in_sizes, int n_in,
                              void* d_out, int out_size, void* d_ws, size_t ws_size,
                              hipStream_t stream) {
    const float* x   = (const float*)d_in[0];
    const float* Wxz = (const float*)d_in[1];
    const float* bxz = (const float*)d_in[2];
    const float* Whz = (const float*)d_in[3];
    const float* bhz = (const float*)d_in[4];
    const float* Wxr = (const float*)d_in[5];
    const float* bxr = (const float*)d_in[6];
    const float* Whr = (const float*)d_in[7];
    const float* bhr = (const float*)d_in[8];
    const float* Wxh = (const float*)d_in[9];
    const float* bxh = (const float*)d_in[10];
    const float* Whh = (const float*)d_in[11];
    const float* bhh = (const float*)d_in[12];
    const float* Why = (const float*)d_in[13];
    const float* bhy = (const float*)d_in[14];

    char* ws = (char*)d_ws;
    size_t off = 0;
    auto alloc = [&](size_t bytes) { char* p = ws + off; off += (bytes + 255) & ~(size_t)255; return p; };
    unsigned short* Whc   = (unsigned short*)alloc((size_t)3 * HID * HID * 2);
    unsigned short* Wxc   = (unsigned short*)alloc((size_t)3 * HID * INF * 2);
    unsigned short* Whyb  = (unsigned short*)alloc((size_t)OUTF * HID * 2);
    float*          bias2 = (float*)alloc((size_t)2 * HID * 4);
    unsigned short* hsbuf = (unsigned short*)alloc((size_t)(SEQL + 1) * BATCH * HID * 2);
    unsigned int*   flags = (unsigned int*)alloc(1024);
    unsigned short* x_bf  = (unsigned short*)d_out;  // dead until the final GEMM

    if (off > ws_size) {
        fail_sentinel<<<dim3(1), dim3(1), 0, stream>>>((float*)d_out);
        return;
    }

    auto cvt = [&](const float* s, unsigned short* d, size_t n) {
        cvt_f32_bf16<<<dim3((unsigned)((n / 4 + 255) / 256)), dim3(256), 0, stream>>>(s, d, (int)n);
    };
    cvt(x, x_bf, (size_t)SB * INF);
    cvt(Whz, Whc, (size_t)HID * HID);
    cvt(Whr, Whc + (size_t)HID * HID, (size_t)HID * HID);
    cvt(Whh, Whc + (size_t)2 * HID * HID, (size_t)HID * HID);
    cvt(Wxz, Wxc, (size_t)HID * INF);
    cvt(Wxr, Wxc + (size_t)HID * INF, (size_t)HID * INF);
    cvt(Wxh, Wxc + (size_t)2 * HID * INF, (size_t)HID * INF);
    cvt(Why, Whyb, (size_t)OUTF * HID);
    make_bias2<<<dim3(8), dim3(256), 0, stream>>>(bxz, bhz, bxr, bhr, bias2);
    (void)hipMemsetAsync(flags, 0, 1024, stream);   // reset per launch (graph-replay safe)

    gru_scan<<<dim3(256), dim3(192), 0, stream>>>(Whc, Wxc, x_bf, hsbuf, bias2, bxh, bhh, flags);

    gemm_nt_f32<<<dim3((SB / 128) * (OUTF / 128)), dim3(256), 0, stream>>>(
        hsbuf + (size_t)BATCH * HID, HID, Whyb, HID, bhy, (float*)d_out, OUTF, HID);
}